// Round 6
// baseline (410.342 us; speedup 1.0000x reference)
//
#include <hip/hip_runtime.h>
#include <cstdint>
#include <cstddef>

// N=50000 nodes, E=800000 edges, F_in=512, H=128, C=64.
constexpr int FIN = 512;
constexpr int HD  = 128;
constexpr int CD  = 64;

typedef __attribute__((ext_vector_type(8))) short short8;   // 8 bf16 = 4 VGPRs
typedef __attribute__((ext_vector_type(4))) float f32x4;    // MFMA acc

__device__ inline unsigned short f2bf(float f) {  // RNE fp32->bf16
  unsigned int u = __float_as_uint(f);
  u += 0x7fffu + ((u >> 16) & 1u);
  return (unsigned short)(u >> 16);
}
__device__ inline float bf_lo(unsigned int v) { return __uint_as_float(v << 16); }
__device__ inline float bf_hi(unsigned int v) { return __uint_as_float(v & 0xffff0000u); }
__device__ inline float bf1(unsigned short v) { return __uint_as_float((unsigned int)v << 16); }

// ---------------- prep: weight cvt/transpose + zero cnt/ticket/flag ----------------

__global__ __launch_bounds__(256) void prep(const float* __restrict__ W1,
                                            const float* __restrict__ W2,
                                            unsigned short* __restrict__ w1t,
                                            unsigned short* __restrict__ w2t,
                                            int* __restrict__ cnt,
                                            int* __restrict__ ticket,
                                            int* __restrict__ flag, int n, int nb) {
  int idx = blockIdx.x * 256 + threadIdx.x;
  if (idx < FIN * HD) {
    int k = idx >> 7, c = idx & 127;
    w1t[(size_t)c * FIN + k] = f2bf(W1[idx]);
  } else if (idx < FIN * HD + HD * CD) {
    int j = idx - FIN * HD;
    int k = j >> 6, c = j & 63;
    w2t[(size_t)c * HD + k] = f2bf(W2[j]);
  }
  if (idx < n) cnt[idx] = 0;
  else if (idx < n + nb) flag[idx - n] = 0;
  else if (idx == n + nb) *ticket = 0;
}

// ---------------- hist ----------------

__global__ __launch_bounds__(256) void hist_kernel(const int* __restrict__ dst, int E,
                                                   int* __restrict__ cnt) {
  int i = blockIdx.x * 256 + threadIdx.x;
  if (i < E) atomicAdd(&cnt[dst[i]], 1);
}

// ---------------- single-kernel chained exclusive scan (2048 elems/block) ----------------
// Ticket-ordered publish: block with ticket b waits only on tickets < b, which
// started earlier -> no deadlock under any dispatch order. Device-scope
// atomics for cross-XCD visibility.

__global__ __launch_bounds__(256) void scan_chain(const int* __restrict__ cnt,
                                                  int* __restrict__ off,
                                                  int* __restrict__ cur, int n,
                                                  int* __restrict__ ticket,
                                                  int* __restrict__ partial,
                                                  int* __restrict__ flag) {
  __shared__ int sh[256];
  __shared__ int sbid, sprev;
  int t = threadIdx.x;
  if (t == 0) sbid = atomicAdd(ticket, 1);
  __syncthreads();
  const int bid  = sbid;
  const int base = bid * 2048 + t * 8;
  int v[8];
  int local = 0;
#pragma unroll
  for (int j = 0; j < 8; ++j) {
    v[j] = (base + j < n) ? cnt[base + j] : 0;
    local += v[j];
  }
  sh[t] = local;
  __syncthreads();
  for (int o = 1; o < 256; o <<= 1) {
    int u = (t >= o) ? sh[t - o] : 0;
    __syncthreads();
    sh[t] += u;
    __syncthreads();
  }
  if (t == 0) {
    int prev = 0;
    if (bid > 0) {
      while (__hip_atomic_load(&flag[bid - 1], __ATOMIC_ACQUIRE,
                               __HIP_MEMORY_SCOPE_AGENT) != 1) {}
      prev = partial[bid - 1];
    }
    partial[bid] = prev + sh[255];
    __hip_atomic_store(&flag[bid], 1, __ATOMIC_RELEASE, __HIP_MEMORY_SCOPE_AGENT);
    sprev = prev;
  }
  __syncthreads();
  int run = sprev + sh[t] - local;
#pragma unroll
  for (int j = 0; j < 8; ++j) {
    if (base + j < n) { off[base + j] = run; cur[base + j] = run; }
    run += v[j];
  }
}

// ---------------- scatter ----------------

__global__ __launch_bounds__(256) void scatter_kernel(const int* __restrict__ src,
                                                      const int* __restrict__ dst,
                                                      const float* __restrict__ ew, int E,
                                                      int* __restrict__ cur,
                                                      int2* __restrict__ sew) {
  int i = blockIdx.x * 256 + threadIdx.x;
  if (i < E) {
    int d = dst[i];
    int p = atomicAdd(&cur[d], 1);
    sew[p] = make_int2(src[i], __float_as_int(ew[i]));
  }
}

// ---------------- GEMM1 (MFMA bf16): h1b[M,128](bf16) = x @ W1 ----------------
// 128x128 tile / 256-thr block (4 waves), BK=32, wave = 2 m-tiles x 8 n-tiles.

__global__ __launch_bounds__(256) void gemm1_mfma(const float* __restrict__ x,
                                                  const unsigned short* __restrict__ w1t,
                                                  unsigned short* __restrict__ h1b, int M) {
  __shared__ unsigned short As[128][40];
  __shared__ unsigned short Bs[128][40];
  const int t    = threadIdx.x;
  const int wave = t >> 6;
  const int lane = t & 63;
  const int l15  = lane & 15;
  const int quad = lane >> 4;
  const int m0   = blockIdx.x * 128;

  const int sr = t >> 1;        // staging row 0..127
  const int sk = (t & 1) * 16;  // staging k: 0 or 16

  const bool aok = (m0 + sr) < M;
  const float* xrow = x + (size_t)(m0 + sr) * FIN + sk;
  const unsigned short* brow = w1t + (size_t)sr * FIN + sk;

  f32x4 acc[2][8];
#pragma unroll
  for (int i = 0; i < 2; ++i)
#pragma unroll
    for (int j = 0; j < 8; ++j) acc[i][j] = (f32x4)0.f;

  for (int k0 = 0; k0 < FIN; k0 += 32) {
    float4 a0 = make_float4(0.f, 0.f, 0.f, 0.f), a1 = a0, a2 = a0, a3 = a0;
    if (aok) {
      a0 = *(const float4*)(xrow + k0);
      a1 = *(const float4*)(xrow + k0 + 4);
      a2 = *(const float4*)(xrow + k0 + 8);
      a3 = *(const float4*)(xrow + k0 + 12);
    }
    uint4 b0 = *(const uint4*)(brow + k0);
    uint4 b1 = *(const uint4*)(brow + k0 + 8);
    __syncthreads();
    unsigned short tmp[16];
    tmp[0]  = f2bf(a0.x); tmp[1]  = f2bf(a0.y); tmp[2]  = f2bf(a0.z); tmp[3]  = f2bf(a0.w);
    tmp[4]  = f2bf(a1.x); tmp[5]  = f2bf(a1.y); tmp[6]  = f2bf(a1.z); tmp[7]  = f2bf(a1.w);
    tmp[8]  = f2bf(a2.x); tmp[9]  = f2bf(a2.y); tmp[10] = f2bf(a2.z); tmp[11] = f2bf(a2.w);
    tmp[12] = f2bf(a3.x); tmp[13] = f2bf(a3.y); tmp[14] = f2bf(a3.z); tmp[15] = f2bf(a3.w);
    *(uint4*)&As[sr][sk]     = ((const uint4*)tmp)[0];
    *(uint4*)&As[sr][sk + 8] = ((const uint4*)tmp)[1];
    *(uint4*)&Bs[sr][sk]     = b0;
    *(uint4*)&Bs[sr][sk + 8] = b1;
    __syncthreads();
    short8 af0 = *(const short8*)&As[wave * 32 + l15][quad * 8];
    short8 af1 = *(const short8*)&As[wave * 32 + 16 + l15][quad * 8];
#pragma unroll
    for (int nt = 0; nt < 8; ++nt) {
      short8 bf = *(const short8*)&Bs[nt * 16 + l15][quad * 8];
      acc[0][nt] = __builtin_amdgcn_mfma_f32_16x16x32_bf16(af0, bf, acc[0][nt], 0, 0, 0);
      acc[1][nt] = __builtin_amdgcn_mfma_f32_16x16x32_bf16(af1, bf, acc[1][nt], 0, 0, 0);
    }
  }
#pragma unroll
  for (int mt = 0; mt < 2; ++mt) {
    const int row0 = m0 + wave * 32 + mt * 16 + quad * 4;
#pragma unroll
    for (int r = 0; r < 4; ++r) {
      int row = row0 + r;
      if (row < M) {
        unsigned short* orow = h1b + (size_t)row * HD + l15;
#pragma unroll
        for (int nt = 0; nt < 8; ++nt) orow[nt * 16] = f2bf(acc[mt][nt][r]);
      }
    }
  }
}

// ---------------- fused agg1 (+bias/relu/dropout) -> LDS -> GEMM2 -> h2b ----------------
// Block = 64 nodes. Phase 1: wave w aggregates its own 16 rows into As (no
// cross-wave As dependency); 8-deep edge unroll for MLP. Phase 2: 64x64 MFMA
// GEMM vs LDS-resident W2 (Bs needs the one barrier).

__global__ __launch_bounds__(256) void agg1_gemm2(const unsigned int* __restrict__ h1b,
                                                  const float* __restrict__ b1,
                                                  const float* __restrict__ dm,
                                                  const int* __restrict__ off,
                                                  const int* __restrict__ cnt,
                                                  const int2* __restrict__ sew,
                                                  const unsigned short* __restrict__ w2t,
                                                  unsigned short* __restrict__ h2b, int N) {
  __shared__ unsigned short As[64][136];  // [node][feature], 16B-aligned rows
  __shared__ unsigned short Bs[64][136];  // [class][feature]
  const int t    = threadIdx.x;
  const int wave = t >> 6;
  const int lane = t & 63;
  const int l15  = lane & 15;
  const int quad = lane >> 4;
  const int m0   = blockIdx.x * 64;

  {  // stage W2 -> Bs (64 rows x 128 k)
    const int rb = t >> 2, kb = (t & 3) * 32;
    const unsigned short* srcp = w2t + (size_t)rb * HD + kb;
#pragma unroll
    for (int j = 0; j < 4; ++j)
      *(uint4*)&Bs[rb][kb + j * 8] = *(const uint4*)(srcp + j * 8);
  }

  // Phase 1: aggregate 16 nodes per wave into As rows (lane = 2 features)
  for (int i = 0; i < 16; ++i) {
    const int row  = wave * 16 + i;
    const int node = m0 + row;
    unsigned int pack = 0;
    if (node < N) {
      const int start = off[node];
      const int deg   = cnt[node];
      const int2* ep  = sew + start;
      float a0 = 0.f, a1 = 0.f, c0 = 0.f, c1 = 0.f;
      float e0 = 0.f, e1 = 0.f, g0 = 0.f, g1 = 0.f;
      int e = 0;
      for (; e + 8 <= deg; e += 8) {
        int2 p0 = ep[e + 0], p1 = ep[e + 1], p2 = ep[e + 2], p3 = ep[e + 3];
        int2 p4 = ep[e + 4], p5 = ep[e + 5], p6 = ep[e + 6], p7 = ep[e + 7];
        unsigned int v0 = h1b[(size_t)p0.x * 64 + lane];
        unsigned int v1 = h1b[(size_t)p1.x * 64 + lane];
        unsigned int v2 = h1b[(size_t)p2.x * 64 + lane];
        unsigned int v3 = h1b[(size_t)p3.x * 64 + lane];
        unsigned int v4 = h1b[(size_t)p4.x * 64 + lane];
        unsigned int v5 = h1b[(size_t)p5.x * 64 + lane];
        unsigned int v6 = h1b[(size_t)p6.x * 64 + lane];
        unsigned int v7 = h1b[(size_t)p7.x * 64 + lane];
        float w0 = __int_as_float(p0.y), w1 = __int_as_float(p1.y);
        float w2 = __int_as_float(p2.y), w3 = __int_as_float(p3.y);
        float w4 = __int_as_float(p4.y), w5 = __int_as_float(p5.y);
        float w6 = __int_as_float(p6.y), w7 = __int_as_float(p7.y);
        a0 = fmaf(bf_lo(v0), w0, a0); a1 = fmaf(bf_hi(v0), w0, a1);
        c0 = fmaf(bf_lo(v1), w1, c0); c1 = fmaf(bf_hi(v1), w1, c1);
        e0 = fmaf(bf_lo(v2), w2, e0); e1 = fmaf(bf_hi(v2), w2, e1);
        g0 = fmaf(bf_lo(v3), w3, g0); g1 = fmaf(bf_hi(v3), w3, g1);
        a0 = fmaf(bf_lo(v4), w4, a0); a1 = fmaf(bf_hi(v4), w4, a1);
        c0 = fmaf(bf_lo(v5), w5, c0); c1 = fmaf(bf_hi(v5), w5, c1);
        e0 = fmaf(bf_lo(v6), w6, e0); e1 = fmaf(bf_hi(v6), w6, e1);
        g0 = fmaf(bf_lo(v7), w7, g0); g1 = fmaf(bf_hi(v7), w7, g1);
      }
      for (; e + 4 <= deg; e += 4) {
        int2 p0 = ep[e + 0], p1 = ep[e + 1], p2 = ep[e + 2], p3 = ep[e + 3];
        unsigned int v0 = h1b[(size_t)p0.x * 64 + lane];
        unsigned int v1 = h1b[(size_t)p1.x * 64 + lane];
        unsigned int v2 = h1b[(size_t)p2.x * 64 + lane];
        unsigned int v3 = h1b[(size_t)p3.x * 64 + lane];
        float w0 = __int_as_float(p0.y), w1 = __int_as_float(p1.y);
        float w2 = __int_as_float(p2.y), w3 = __int_as_float(p3.y);
        a0 = fmaf(bf_lo(v0), w0, a0); a1 = fmaf(bf_hi(v0), w0, a1);
        c0 = fmaf(bf_lo(v1), w1, c0); c1 = fmaf(bf_hi(v1), w1, c1);
        e0 = fmaf(bf_lo(v2), w2, e0); e1 = fmaf(bf_hi(v2), w2, e1);
        g0 = fmaf(bf_lo(v3), w3, g0); g1 = fmaf(bf_hi(v3), w3, g1);
      }
      for (; e < deg; ++e) {
        int2 p = ep[e];
        unsigned int v = h1b[(size_t)p.x * 64 + lane];
        float w = __int_as_float(p.y);
        a0 = fmaf(bf_lo(v), w, a0); a1 = fmaf(bf_hi(v), w, a1);
      }
      a0 += c0 + e0 + g0; a1 += c1 + e1 + g1;
      const int f0 = lane * 2;
      float2 bb = *(const float2*)(b1 + f0);
      float2 dd = *(const float2*)(dm + (size_t)node * HD + f0);
      float r0 = fmaxf(a0 + bb.x, 0.f) * ((dd.x >= 0.5f) ? 2.0f : 0.0f);
      float r1 = fmaxf(a1 + bb.y, 0.f) * ((dd.y >= 0.5f) ? 2.0f : 0.0f);
      pack = (unsigned int)f2bf(r0) | ((unsigned int)f2bf(r1) << 16);
    }
    *(unsigned int*)&As[row][lane * 2] = pack;
  }
  __syncthreads();  // Bs staged by all threads; As rows are wave-local

  // Phase 2: GEMM 64x64, K=128 from LDS. Wave = 1 m-tile x 4 n-tiles.
  f32x4 acc[4];
#pragma unroll
  for (int nt = 0; nt < 4; ++nt) acc[nt] = (f32x4)0.f;
#pragma unroll
  for (int ks = 0; ks < 4; ++ks) {
    const int k0 = ks * 32 + quad * 8;
    short8 af = *(const short8*)&As[wave * 16 + l15][k0];
#pragma unroll
    for (int nt = 0; nt < 4; ++nt) {
      short8 bf = *(const short8*)&Bs[nt * 16 + l15][k0];
      acc[nt] = __builtin_amdgcn_mfma_f32_16x16x32_bf16(af, bf, acc[nt], 0, 0, 0);
    }
  }
  const int row0 = m0 + wave * 16 + quad * 4;
#pragma unroll
  for (int r = 0; r < 4; ++r) {
    int row = row0 + r;
    if (row < N) {
      unsigned short* orow = h2b + (size_t)row * CD + l15;
#pragma unroll
      for (int nt = 0; nt < 4; ++nt) orow[nt * 16] = f2bf(acc[nt][r]);
    }
  }
}

// ---------------- agg2 + bias + log_softmax: wave/node, 8-deep unroll ----------------

__global__ __launch_bounds__(256) void agg2_kernel(const unsigned short* __restrict__ h2b,
                                                   const float* __restrict__ b2,
                                                   const int* __restrict__ off,
                                                   const int* __restrict__ cnt,
                                                   const int2* __restrict__ sew,
                                                   float* __restrict__ out, int N) {
  const int wave = threadIdx.x >> 6;
  const int c    = threadIdx.x & 63;
  const int node = blockIdx.x * 4 + wave;
  if (node >= N) return;
  const int start = off[node];
  const int deg   = cnt[node];
  const int2* ep  = sew + start;

  float acc = b2[c], a1 = 0.f, a2 = 0.f, a3 = 0.f;
  int e = 0;
  for (; e + 8 <= deg; e += 8) {
    int2 p0 = ep[e + 0], p1 = ep[e + 1], p2 = ep[e + 2], p3 = ep[e + 3];
    int2 p4 = ep[e + 4], p5 = ep[e + 5], p6 = ep[e + 6], p7 = ep[e + 7];
    float v0 = bf1(h2b[(size_t)p0.x * CD + c]);
    float v1 = bf1(h2b[(size_t)p1.x * CD + c]);
    float v2 = bf1(h2b[(size_t)p2.x * CD + c]);
    float v3 = bf1(h2b[(size_t)p3.x * CD + c]);
    float v4 = bf1(h2b[(size_t)p4.x * CD + c]);
    float v5 = bf1(h2b[(size_t)p5.x * CD + c]);
    float v6 = bf1(h2b[(size_t)p6.x * CD + c]);
    float v7 = bf1(h2b[(size_t)p7.x * CD + c]);
    acc = fmaf(v0, __int_as_float(p0.y), acc);
    a1  = fmaf(v1, __int_as_float(p1.y), a1);
    a2  = fmaf(v2, __int_as_float(p2.y), a2);
    a3  = fmaf(v3, __int_as_float(p3.y), a3);
    acc = fmaf(v4, __int_as_float(p4.y), acc);
    a1  = fmaf(v5, __int_as_float(p5.y), a1);
    a2  = fmaf(v6, __int_as_float(p6.y), a2);
    a3  = fmaf(v7, __int_as_float(p7.y), a3);
  }
  for (; e + 4 <= deg; e += 4) {
    int2 p0 = ep[e + 0], p1 = ep[e + 1], p2 = ep[e + 2], p3 = ep[e + 3];
    float v0 = bf1(h2b[(size_t)p0.x * CD + c]);
    float v1 = bf1(h2b[(size_t)p1.x * CD + c]);
    float v2 = bf1(h2b[(size_t)p2.x * CD + c]);
    float v3 = bf1(h2b[(size_t)p3.x * CD + c]);
    acc = fmaf(v0, __int_as_float(p0.y), acc);
    a1  = fmaf(v1, __int_as_float(p1.y), a1);
    a2  = fmaf(v2, __int_as_float(p2.y), a2);
    a3  = fmaf(v3, __int_as_float(p3.y), a3);
  }
  for (; e < deg; ++e) {
    int2 p = ep[e];
    acc = fmaf(bf1(h2b[(size_t)p.x * CD + c]), __int_as_float(p.y), acc);
  }
  acc += a1 + a2 + a3;

  float m = acc;
#pragma unroll
  for (int o = 32; o > 0; o >>= 1) m = fmaxf(m, __shfl_xor(m, o, 64));
  float ex = __expf(acc - m);
  float ssum = ex;
#pragma unroll
  for (int o = 32; o > 0; o >>= 1) ssum += __shfl_xor(ssum, o, 64);
  out[(size_t)node * CD + c] = (acc - m) - __logf(ssum);
}

// ---------------- launch ----------------

extern "C" void kernel_launch(void* const* d_in, const int* in_sizes, int n_in,
                              void* d_out, int out_size, void* d_ws, size_t ws_size,
                              hipStream_t stream) {
  const float* x  = (const float*)d_in[0];
  const float* ew = (const float*)d_in[1];
  const float* W1 = (const float*)d_in[2];
  const float* b1 = (const float*)d_in[3];
  const float* W2 = (const float*)d_in[4];
  const float* b2 = (const float*)d_in[5];
  const float* dm = (const float*)d_in[6];
  const int*   ei = (const int*)d_in[7];
  float* out = (float*)d_out;

  const int E = in_sizes[1];
  const int N = in_sizes[6] / HD;
  const int* srcp = ei;
  const int* dstp = ei + E;
  const int nb = (N + 2047) / 2048;  // 25 scan blocks

  uint8_t* w = (uint8_t*)d_ws;
  size_t o = 0;
  auto alloc = [&](size_t bytes) -> void* {
    void* p = w + o;
    o = (o + bytes + 255) & ~(size_t)255;
    return p;
  };
  int*   off    = (int*)alloc((size_t)N * 4);
  int*   cnt    = (int*)alloc((size_t)N * 4);
  int*   cur    = (int*)alloc((size_t)N * 4);
  int2*  sew    = (int2*)alloc((size_t)E * 8);
  unsigned short* h1b = (unsigned short*)alloc((size_t)N * HD * 2);
  unsigned short* h2b = (unsigned short*)alloc((size_t)N * CD * 2);
  unsigned short* w1t = (unsigned short*)alloc((size_t)FIN * HD * 2);
  unsigned short* w2t = (unsigned short*)alloc((size_t)HD * CD * 2);
  int*   ticket  = (int*)alloc(4);
  int*   partial = (int*)alloc((size_t)nb * 4);
  int*   flag    = (int*)alloc((size_t)nb * 4);

  const int prep_threads = FIN * HD + HD * CD;  // covers N+nb+1 too (73728 > 50026)
  prep<<<(prep_threads + 255) / 256, 256, 0, stream>>>(W1, W2, w1t, w2t, cnt, ticket, flag, N, nb);
  hist_kernel<<<(E + 255) / 256, 256, 0, stream>>>(dstp, E, cnt);
  scan_chain<<<nb, 256, 0, stream>>>(cnt, off, cur, N, ticket, partial, flag);
  scatter_kernel<<<(E + 255) / 256, 256, 0, stream>>>(srcp, dstp, ew, E, cur, sew);
  gemm1_mfma<<<(N + 127) / 128, 256, 0, stream>>>(x, w1t, h1b, N);
  agg1_gemm2<<<(N + 63) / 64, 256, 0, stream>>>((const unsigned int*)h1b, b1, dm, off, cnt, sew, w2t, h2b, N);
  agg2_kernel<<<(N + 3) / 4, 256, 0, stream>>>(h2b, b2, off, cnt, sew, out, N);
}

// Round 8
// 360.497 us; speedup vs baseline: 1.1383x; 1.1383x over previous
//
#include <hip/hip_runtime.h>
#include <cstdint>
#include <cstddef>

// N=50000 nodes, E=800000 edges, F_in=512, H=128, C=64.
constexpr int FIN = 512;
constexpr int HD  = 128;
constexpr int CD  = 64;

typedef __attribute__((ext_vector_type(8))) short short8;   // 8 bf16 = 4 VGPRs
typedef __attribute__((ext_vector_type(4))) float f32x4;    // MFMA acc

__device__ inline unsigned short f2bf(float f) {  // RNE fp32->bf16
  unsigned int u = __float_as_uint(f);
  u += 0x7fffu + ((u >> 16) & 1u);
  return (unsigned short)(u >> 16);
}
__device__ inline float bf_lo(unsigned int v) { return __uint_as_float(v << 16); }
__device__ inline float bf_hi(unsigned int v) { return __uint_as_float(v & 0xffff0000u); }
__device__ inline float bf1(unsigned short v) { return __uint_as_float((unsigned int)v << 16); }

// ---------------- prep: weight cvt/transpose + zero cnt ----------------

__global__ __launch_bounds__(256) void prep(const float* __restrict__ W1,
                                            const float* __restrict__ W2,
                                            unsigned short* __restrict__ w1t,
                                            unsigned short* __restrict__ w2t,
                                            int* __restrict__ cnt, int n) {
  int idx = blockIdx.x * 256 + threadIdx.x;
  if (idx < FIN * HD) {
    int k = idx >> 7, c = idx & 127;
    w1t[(size_t)c * FIN + k] = f2bf(W1[idx]);
  } else if (idx < FIN * HD + HD * CD) {
    int j = idx - FIN * HD;
    int k = j >> 6, c = j & 63;
    w2t[(size_t)c * HD + k] = f2bf(W2[j]);
  }
  if (idx < n) cnt[idx] = 0;
}

// ---------------- hist ----------------

__global__ __launch_bounds__(256) void hist_kernel(const int* __restrict__ dst, int E,
                                                   int* __restrict__ cnt) {
  int i = blockIdx.x * 256 + threadIdx.x;
  if (i < E) atomicAdd(&cnt[dst[i]], 1);
}

// ---------------- deterministic 2-kernel scan (no inter-block sync) ----------------
// scan_a: per-block (2048 elems) sums. scan_c: block offset = wave-reduce of
// bsum[0..bid) (nb<=64), then local scan. No spin-waits, no cross-XCD hazards.

__global__ __launch_bounds__(256) void scan_a(const int* __restrict__ cnt,
                                              int* __restrict__ bs, int n) {
  __shared__ int sh[256];
  int t = threadIdx.x;
  int base = blockIdx.x * 2048;
  int s = 0;
#pragma unroll
  for (int j = 0; j < 8; ++j) {
    int idx = base + j * 256 + t;
    if (idx < n) s += cnt[idx];
  }
  sh[t] = s;
  __syncthreads();
  for (int o = 128; o > 0; o >>= 1) {
    if (t < o) sh[t] += sh[t + o];
    __syncthreads();
  }
  if (t == 0) bs[blockIdx.x] = sh[0];
}

__global__ __launch_bounds__(256) void scan_c(const int* __restrict__ cnt,
                                              const int* __restrict__ bs,
                                              int* __restrict__ off,
                                              int* __restrict__ cur, int n) {
  __shared__ int sh[256];
  __shared__ int sbase;
  const int t   = threadIdx.x;
  const int bid = blockIdx.x;
  if (t < 64) {  // block offset = sum of earlier blocks' sums (bid <= 63)
    int v = (t < bid) ? bs[t] : 0;
#pragma unroll
    for (int o = 32; o > 0; o >>= 1) v += __shfl_xor(v, o, 64);
    if (t == 0) sbase = v;
  }
  const int base = bid * 2048 + t * 8;
  int v[8];
  int local = 0;
#pragma unroll
  for (int j = 0; j < 8; ++j) {
    v[j] = (base + j < n) ? cnt[base + j] : 0;
    local += v[j];
  }
  sh[t] = local;
  __syncthreads();
  for (int o = 1; o < 256; o <<= 1) {
    int u = (t >= o) ? sh[t - o] : 0;
    __syncthreads();
    sh[t] += u;
    __syncthreads();
  }
  int run = sbase + sh[t] - local;
#pragma unroll
  for (int j = 0; j < 8; ++j) {
    if (base + j < n) { off[base + j] = run; cur[base + j] = run; }
    run += v[j];
  }
}

// ---------------- scatter ----------------

__global__ __launch_bounds__(256) void scatter_kernel(const int* __restrict__ src,
                                                      const int* __restrict__ dst,
                                                      const float* __restrict__ ew, int E,
                                                      int* __restrict__ cur,
                                                      int2* __restrict__ sew) {
  int i = blockIdx.x * 256 + threadIdx.x;
  if (i < E) {
    int d = dst[i];
    int p = atomicAdd(&cur[d], 1);
    sew[p] = make_int2(src[i], __float_as_int(ew[i]));
  }
}

// ---------------- GEMM1 (MFMA bf16): h1b[M,128](bf16) = x @ W1 ----------------
// 128x128 tile / 256-thr block (4 waves), BK=32, wave = 2 m-tiles x 8 n-tiles.

__global__ __launch_bounds__(256) void gemm1_mfma(const float* __restrict__ x,
                                                  const unsigned short* __restrict__ w1t,
                                                  unsigned short* __restrict__ h1b, int M) {
  __shared__ unsigned short As[128][40];
  __shared__ unsigned short Bs[128][40];
  const int t    = threadIdx.x;
  const int wave = t >> 6;
  const int lane = t & 63;
  const int l15  = lane & 15;
  const int quad = lane >> 4;
  const int m0   = blockIdx.x * 128;

  const int sr = t >> 1;        // staging row 0..127
  const int sk = (t & 1) * 16;  // staging k: 0 or 16

  const bool aok = (m0 + sr) < M;
  const float* xrow = x + (size_t)(m0 + sr) * FIN + sk;
  const unsigned short* brow = w1t + (size_t)sr * FIN + sk;

  f32x4 acc[2][8];
#pragma unroll
  for (int i = 0; i < 2; ++i)
#pragma unroll
    for (int j = 0; j < 8; ++j) acc[i][j] = (f32x4)0.f;

  for (int k0 = 0; k0 < FIN; k0 += 32) {
    float4 a0 = make_float4(0.f, 0.f, 0.f, 0.f), a1 = a0, a2 = a0, a3 = a0;
    if (aok) {
      a0 = *(const float4*)(xrow + k0);
      a1 = *(const float4*)(xrow + k0 + 4);
      a2 = *(const float4*)(xrow + k0 + 8);
      a3 = *(const float4*)(xrow + k0 + 12);
    }
    uint4 b0 = *(const uint4*)(brow + k0);
    uint4 b1 = *(const uint4*)(brow + k0 + 8);
    __syncthreads();
    unsigned short tmp[16];
    tmp[0]  = f2bf(a0.x); tmp[1]  = f2bf(a0.y); tmp[2]  = f2bf(a0.z); tmp[3]  = f2bf(a0.w);
    tmp[4]  = f2bf(a1.x); tmp[5]  = f2bf(a1.y); tmp[6]  = f2bf(a1.z); tmp[7]  = f2bf(a1.w);
    tmp[8]  = f2bf(a2.x); tmp[9]  = f2bf(a2.y); tmp[10] = f2bf(a2.z); tmp[11] = f2bf(a2.w);
    tmp[12] = f2bf(a3.x); tmp[13] = f2bf(a3.y); tmp[14] = f2bf(a3.z); tmp[15] = f2bf(a3.w);
    *(uint4*)&As[sr][sk]     = ((const uint4*)tmp)[0];
    *(uint4*)&As[sr][sk + 8] = ((const uint4*)tmp)[1];
    *(uint4*)&Bs[sr][sk]     = b0;
    *(uint4*)&Bs[sr][sk + 8] = b1;
    __syncthreads();
    short8 af0 = *(const short8*)&As[wave * 32 + l15][quad * 8];
    short8 af1 = *(const short8*)&As[wave * 32 + 16 + l15][quad * 8];
#pragma unroll
    for (int nt = 0; nt < 8; ++nt) {
      short8 bf = *(const short8*)&Bs[nt * 16 + l15][quad * 8];
      acc[0][nt] = __builtin_amdgcn_mfma_f32_16x16x32_bf16(af0, bf, acc[0][nt], 0, 0, 0);
      acc[1][nt] = __builtin_amdgcn_mfma_f32_16x16x32_bf16(af1, bf, acc[1][nt], 0, 0, 0);
    }
  }
#pragma unroll
  for (int mt = 0; mt < 2; ++mt) {
    const int row0 = m0 + wave * 32 + mt * 16 + quad * 4;
#pragma unroll
    for (int r = 0; r < 4; ++r) {
      int row = row0 + r;
      if (row < M) {
        unsigned short* orow = h1b + (size_t)row * HD + l15;
#pragma unroll
        for (int nt = 0; nt < 8; ++nt) orow[nt * 16] = f2bf(acc[mt][nt][r]);
      }
    }
  }
}

// ---------------- agg1: wave/node (max TLP), 8-deep unroll, bf16 in/out ----------------

__global__ __launch_bounds__(256) void agg1_kernel(const unsigned int* __restrict__ h1b,
                                                   const float* __restrict__ b1,
                                                   const float* __restrict__ dm,
                                                   const int* __restrict__ off,
                                                   const int* __restrict__ cnt,
                                                   const int2* __restrict__ sew,
                                                   unsigned int* __restrict__ hbf, int N) {
  const int wave = threadIdx.x >> 6;
  const int lane = threadIdx.x & 63;
  const int node = blockIdx.x * 4 + wave;
  if (node >= N) return;
  const int start = off[node];
  const int deg   = cnt[node];
  const int2* ep  = sew + start;

  float a0 = 0.f, a1 = 0.f, c0 = 0.f, c1 = 0.f;
  float e0 = 0.f, e1 = 0.f, g0 = 0.f, g1 = 0.f;
  int e = 0;
  for (; e + 8 <= deg; e += 8) {
    int2 p0 = ep[e + 0], p1 = ep[e + 1], p2 = ep[e + 2], p3 = ep[e + 3];
    int2 p4 = ep[e + 4], p5 = ep[e + 5], p6 = ep[e + 6], p7 = ep[e + 7];
    unsigned int v0 = h1b[(size_t)p0.x * 64 + lane];
    unsigned int v1 = h1b[(size_t)p1.x * 64 + lane];
    unsigned int v2 = h1b[(size_t)p2.x * 64 + lane];
    unsigned int v3 = h1b[(size_t)p3.x * 64 + lane];
    unsigned int v4 = h1b[(size_t)p4.x * 64 + lane];
    unsigned int v5 = h1b[(size_t)p5.x * 64 + lane];
    unsigned int v6 = h1b[(size_t)p6.x * 64 + lane];
    unsigned int v7 = h1b[(size_t)p7.x * 64 + lane];
    float w0 = __int_as_float(p0.y), w1 = __int_as_float(p1.y);
    float w2 = __int_as_float(p2.y), w3 = __int_as_float(p3.y);
    float w4 = __int_as_float(p4.y), w5 = __int_as_float(p5.y);
    float w6 = __int_as_float(p6.y), w7 = __int_as_float(p7.y);
    a0 = fmaf(bf_lo(v0), w0, a0); a1 = fmaf(bf_hi(v0), w0, a1);
    c0 = fmaf(bf_lo(v1), w1, c0); c1 = fmaf(bf_hi(v1), w1, c1);
    e0 = fmaf(bf_lo(v2), w2, e0); e1 = fmaf(bf_hi(v2), w2, e1);
    g0 = fmaf(bf_lo(v3), w3, g0); g1 = fmaf(bf_hi(v3), w3, g1);
    a0 = fmaf(bf_lo(v4), w4, a0); a1 = fmaf(bf_hi(v4), w4, a1);
    c0 = fmaf(bf_lo(v5), w5, c0); c1 = fmaf(bf_hi(v5), w5, c1);
    e0 = fmaf(bf_lo(v6), w6, e0); e1 = fmaf(bf_hi(v6), w6, e1);
    g0 = fmaf(bf_lo(v7), w7, g0); g1 = fmaf(bf_hi(v7), w7, g1);
  }
  for (; e + 4 <= deg; e += 4) {
    int2 p0 = ep[e + 0], p1 = ep[e + 1], p2 = ep[e + 2], p3 = ep[e + 3];
    unsigned int v0 = h1b[(size_t)p0.x * 64 + lane];
    unsigned int v1 = h1b[(size_t)p1.x * 64 + lane];
    unsigned int v2 = h1b[(size_t)p2.x * 64 + lane];
    unsigned int v3 = h1b[(size_t)p3.x * 64 + lane];
    float w0 = __int_as_float(p0.y), w1 = __int_as_float(p1.y);
    float w2 = __int_as_float(p2.y), w3 = __int_as_float(p3.y);
    a0 = fmaf(bf_lo(v0), w0, a0); a1 = fmaf(bf_hi(v0), w0, a1);
    c0 = fmaf(bf_lo(v1), w1, c0); c1 = fmaf(bf_hi(v1), w1, c1);
    e0 = fmaf(bf_lo(v2), w2, e0); e1 = fmaf(bf_hi(v2), w2, e1);
    g0 = fmaf(bf_lo(v3), w3, g0); g1 = fmaf(bf_hi(v3), w3, g1);
  }
  for (; e < deg; ++e) {
    int2 p = ep[e];
    unsigned int v = h1b[(size_t)p.x * 64 + lane];
    float w = __int_as_float(p.y);
    a0 = fmaf(bf_lo(v), w, a0); a1 = fmaf(bf_hi(v), w, a1);
  }
  a0 += c0 + e0 + g0; a1 += c1 + e1 + g1;

  const int f0 = lane * 2;
  float2 bb = *(const float2*)(b1 + f0);
  float2 dd = *(const float2*)(dm + (size_t)node * HD + f0);
  float r0 = fmaxf(a0 + bb.x, 0.f) * ((dd.x >= 0.5f) ? 2.0f : 0.0f);
  float r1 = fmaxf(a1 + bb.y, 0.f) * ((dd.y >= 0.5f) ? 2.0f : 0.0f);
  hbf[(size_t)node * 64 + lane] = (unsigned int)f2bf(r0) | ((unsigned int)f2bf(r1) << 16);
}

// ---------------- GEMM2 (MFMA bf16): h2b[M,64](bf16) = h_bf[M,128] @ W2 ----------------
// 128x64 tile / 256-thr block. Wave = 2 m-tiles x 4 n-tiles. BK=32.

__global__ __launch_bounds__(256) void gemm2_mfma(const unsigned short* __restrict__ hbf,
                                                  const unsigned short* __restrict__ w2t,
                                                  unsigned short* __restrict__ h2b, int M) {
  __shared__ unsigned short As[128][40];
  __shared__ unsigned short Bs[64][40];
  const int t    = threadIdx.x;
  const int wave = t >> 6;
  const int lane = t & 63;
  const int l15  = lane & 15;
  const int quad = lane >> 4;
  const int m0   = blockIdx.x * 128;

  const int sr = t >> 1;        // A staging row 0..127
  const int sk = (t & 1) * 16;
  const int rb = t >> 2;        // B staging row 0..63
  const int kb = (t & 3) * 8;   // 4 threads x 8 ushorts = 32

  const bool aok = (m0 + sr) < M;
  const unsigned short* arow = hbf + (size_t)(m0 + sr) * HD + sk;
  const unsigned short* brow = w2t + (size_t)rb * HD + kb;

  f32x4 acc[2][4];
#pragma unroll
  for (int i = 0; i < 2; ++i)
#pragma unroll
    for (int j = 0; j < 4; ++j) acc[i][j] = (f32x4)0.f;

  for (int k0 = 0; k0 < HD; k0 += 32) {
    uint4 av0 = make_uint4(0, 0, 0, 0), av1 = av0;
    if (aok) {
      av0 = *(const uint4*)(arow + k0);
      av1 = *(const uint4*)(arow + k0 + 8);
    }
    uint4 bv = *(const uint4*)(brow + k0);   // 8 ushorts
    __syncthreads();
    *(uint4*)&As[sr][sk]     = av0;
    *(uint4*)&As[sr][sk + 8] = av1;
    *(uint4*)&Bs[rb][kb]     = bv;
    __syncthreads();
    short8 af0 = *(const short8*)&As[wave * 32 + l15][quad * 8];
    short8 af1 = *(const short8*)&As[wave * 32 + 16 + l15][quad * 8];
#pragma unroll
    for (int nt = 0; nt < 4; ++nt) {
      short8 bf = *(const short8*)&Bs[nt * 16 + l15][quad * 8];
      acc[0][nt] = __builtin_amdgcn_mfma_f32_16x16x32_bf16(af0, bf, acc[0][nt], 0, 0, 0);
      acc[1][nt] = __builtin_amdgcn_mfma_f32_16x16x32_bf16(af1, bf, acc[1][nt], 0, 0, 0);
    }
  }
#pragma unroll
  for (int mt = 0; mt < 2; ++mt) {
    const int row0 = m0 + wave * 32 + mt * 16 + quad * 4;
#pragma unroll
    for (int r = 0; r < 4; ++r) {
      int row = row0 + r;
      if (row < M) {
        unsigned short* orow = h2b + (size_t)row * CD + l15;
#pragma unroll
        for (int nt = 0; nt < 4; ++nt) orow[nt * 16] = f2bf(acc[mt][nt][r]);
      }
    }
  }
}

// ---------------- agg2 + bias + log_softmax: wave/node, 8-deep unroll ----------------

__global__ __launch_bounds__(256) void agg2_kernel(const unsigned short* __restrict__ h2b,
                                                   const float* __restrict__ b2,
                                                   const int* __restrict__ off,
                                                   const int* __restrict__ cnt,
                                                   const int2* __restrict__ sew,
                                                   float* __restrict__ out, int N) {
  const int wave = threadIdx.x >> 6;
  const int c    = threadIdx.x & 63;
  const int node = blockIdx.x * 4 + wave;
  if (node >= N) return;
  const int start = off[node];
  const int deg   = cnt[node];
  const int2* ep  = sew + start;

  float acc = b2[c], a1 = 0.f, a2 = 0.f, a3 = 0.f;
  int e = 0;
  for (; e + 8 <= deg; e += 8) {
    int2 p0 = ep[e + 0], p1 = ep[e + 1], p2 = ep[e + 2], p3 = ep[e + 3];
    int2 p4 = ep[e + 4], p5 = ep[e + 5], p6 = ep[e + 6], p7 = ep[e + 7];
    float v0 = bf1(h2b[(size_t)p0.x * CD + c]);
    float v1 = bf1(h2b[(size_t)p1.x * CD + c]);
    float v2 = bf1(h2b[(size_t)p2.x * CD + c]);
    float v3 = bf1(h2b[(size_t)p3.x * CD + c]);
    float v4 = bf1(h2b[(size_t)p4.x * CD + c]);
    float v5 = bf1(h2b[(size_t)p5.x * CD + c]);
    float v6 = bf1(h2b[(size_t)p6.x * CD + c]);
    float v7 = bf1(h2b[(size_t)p7.x * CD + c]);
    acc = fmaf(v0, __int_as_float(p0.y), acc);
    a1  = fmaf(v1, __int_as_float(p1.y), a1);
    a2  = fmaf(v2, __int_as_float(p2.y), a2);
    a3  = fmaf(v3, __int_as_float(p3.y), a3);
    acc = fmaf(v4, __int_as_float(p4.y), acc);
    a1  = fmaf(v5, __int_as_float(p5.y), a1);
    a2  = fmaf(v6, __int_as_float(p6.y), a2);
    a3  = fmaf(v7, __int_as_float(p7.y), a3);
  }
  for (; e + 4 <= deg; e += 4) {
    int2 p0 = ep[e + 0], p1 = ep[e + 1], p2 = ep[e + 2], p3 = ep[e + 3];
    float v0 = bf1(h2b[(size_t)p0.x * CD + c]);
    float v1 = bf1(h2b[(size_t)p1.x * CD + c]);
    float v2 = bf1(h2b[(size_t)p2.x * CD + c]);
    float v3 = bf1(h2b[(size_t)p3.x * CD + c]);
    acc = fmaf(v0, __int_as_float(p0.y), acc);
    a1  = fmaf(v1, __int_as_float(p1.y), a1);
    a2  = fmaf(v2, __int_as_float(p2.y), a2);
    a3  = fmaf(v3, __int_as_float(p3.y), a3);
  }
  for (; e < deg; ++e) {
    int2 p = ep[e];
    acc = fmaf(bf1(h2b[(size_t)p.x * CD + c]), __int_as_float(p.y), acc);
  }
  acc += a1 + a2 + a3;

  float m = acc;
#pragma unroll
  for (int o = 32; o > 0; o >>= 1) m = fmaxf(m, __shfl_xor(m, o, 64));
  float ex = __expf(acc - m);
  float ssum = ex;
#pragma unroll
  for (int o = 32; o > 0; o >>= 1) ssum += __shfl_xor(ssum, o, 64);
  out[(size_t)node * CD + c] = (acc - m) - __logf(ssum);
}

// ---------------- launch ----------------

extern "C" void kernel_launch(void* const* d_in, const int* in_sizes, int n_in,
                              void* d_out, int out_size, void* d_ws, size_t ws_size,
                              hipStream_t stream) {
  const float* x  = (const float*)d_in[0];
  const float* ew = (const float*)d_in[1];
  const float* W1 = (const float*)d_in[2];
  const float* b1 = (const float*)d_in[3];
  const float* W2 = (const float*)d_in[4];
  const float* b2 = (const float*)d_in[5];
  const float* dm = (const float*)d_in[6];
  const int*   ei = (const int*)d_in[7];
  float* out = (float*)d_out;

  const int E = in_sizes[1];
  const int N = in_sizes[6] / HD;
  const int* srcp = ei;
  const int* dstp = ei + E;
  const int nb = (N + 2047) / 2048;  // 25 scan blocks (<=64 supported by scan_c)

  uint8_t* w = (uint8_t*)d_ws;
  size_t o = 0;
  auto alloc = [&](size_t bytes) -> void* {
    void* p = w + o;
    o = (o + bytes + 255) & ~(size_t)255;
    return p;
  };
  int*   off    = (int*)alloc((size_t)N * 4);
  int*   cnt    = (int*)alloc((size_t)N * 4);
  int*   cur    = (int*)alloc((size_t)N * 4);
  int2*  sew    = (int2*)alloc((size_t)E * 8);
  unsigned short* h1b = (unsigned short*)alloc((size_t)N * HD * 2);
  unsigned int*   hbf = (unsigned int*)alloc((size_t)N * HD * 2);
  unsigned short* h2b = (unsigned short*)alloc((size_t)N * CD * 2);
  unsigned short* w1t = (unsigned short*)alloc((size_t)FIN * HD * 2);
  unsigned short* w2t = (unsigned short*)alloc((size_t)HD * CD * 2);
  int*   bsum   = (int*)alloc((size_t)nb * 4);

  const int prep_threads = FIN * HD + HD * CD;  // covers N zeroing too (73728 > 50000)
  prep<<<(prep_threads + 255) / 256, 256, 0, stream>>>(W1, W2, w1t, w2t, cnt, N);
  hist_kernel<<<(E + 255) / 256, 256, 0, stream>>>(dstp, E, cnt);
  scan_a<<<nb, 256, 0, stream>>>(cnt, bsum, N);
  scan_c<<<nb, 256, 0, stream>>>(cnt, bsum, off, cur, N);
  scatter_kernel<<<(E + 255) / 256, 256, 0, stream>>>(srcp, dstp, ew, E, cur, sew);
  gemm1_mfma<<<(N + 127) / 128, 256, 0, stream>>>(x, w1t, h1b, N);
  agg1_kernel<<<(N + 3) / 4, 256, 0, stream>>>((const unsigned int*)h1b, b1, dm, off, cnt, sew, hbf, N);
  gemm2_mfma<<<(N + 127) / 128, 256, 0, stream>>>((const unsigned short*)hbf, w2t, h2b, N);
  agg2_kernel<<<(N + 3) / 4, 256, 0, stream>>>(h2b, b2, off, cnt, sew, out, N);
}